// Round 8
// baseline (105.557 us; speedup 1.0000x reference)
//
#include <hip/hip_runtime.h>
#include <hip/hip_bf16.h>
#include <stdint.h>

typedef __bf16 bf16x8 __attribute__((ext_vector_type(8)));
typedef float  f32x4  __attribute__((ext_vector_type(4)));
typedef float  f32x2  __attribute__((ext_vector_type(2)));
typedef float  f32x16 __attribute__((ext_vector_type(16)));

#define KC 200
#define KB 8                       // k-components per block (32B write chunks: L2-merge ideal)
#define CBASE (-58.8120661251f)    // -0.5 * 64 * log(2*pi)

// ws layout:
//   Lt  : bf16 [200][64][64] ([k][e][d])   bytes        0 .. 1638400
//   muL : f32  [200][64]                   1638400 .. 1689600
//   ckh : f32  [2][200] (partial logdets)  1689600 .. 1691200

// ---------------- prepass: 400 blocks = (k, e-half). transpose+convert, muL, ck halves ----------------
__global__ __launch_bounds__(256) void prep_b(const float* __restrict__ prec,
                                              const float* __restrict__ means,
                                              __bf16* __restrict__ Lt,
                                              float* __restrict__ muL,
                                              float* __restrict__ ckh) {
    __shared__ float sP[64][40];   // [d][e-in-half], padded
    __shared__ float sM[64];
    const int k = blockIdx.x >> 1, h = blockIdx.x & 1, tid = threadIdx.x;
    const float* pk = prec + (size_t)k * 4096 + h * 32;
    #pragma unroll
    for (int it = 0; it < 2; ++it) {
        int f4 = tid + it * 256;            // 512 float4 = 64 rows x 8
        int d = f4 >> 3, c = (f4 & 7) * 4;
        float4 v = *(const float4*)(pk + (size_t)d * 64 + c);
        *(float4*)&sP[d][c] = v;
    }
    if (tid < 16) *(float4*)&sM[tid * 4] = ((const float4*)(means + (size_t)k * 64))[tid];
    __syncthreads();
    {
        int e = tid >> 3, d0 = (tid & 7) * 8;
        bf16x8 o;
        #pragma unroll
        for (int i = 0; i < 8; ++i) o[i] = (__bf16)sP[d0 + i][e];
        *(bf16x8*)(Lt + (size_t)k * 4096 + (size_t)(h * 32 + e) * 64 + d0) = o;
    }
    if (tid < 32) {
        int e = tid;
        float m = 0.f;
        #pragma unroll 8
        for (int d = 0; d < 64; ++d) m = fmaf(sM[d], sP[d][e], m);
        muL[k * 64 + h * 32 + e] = m;
        float l = __logf(sP[h * 32 + e][e]);   // diag entry (h*32+e, h*32+e)
        #pragma unroll
        for (int mm = 16; mm >= 1; mm >>= 1) l += __shfl_xor(l, mm, 64);
        if (e == 0) ckh[h * KC + k] = l;
    }
}

// ---------------- main: swapped-operand fused GEMM + squared-distance, 32x32x16 MFMA ----------------
// acc[e][row] = Lt_k . x^T - muL, with the -muL folded in as an extra K=16 MFMA slice:
//   A_mu[e][0] = muL_bf16[e], B_mu[0][row] = -1  (other K-slots zero).
// 32x32x16 layouts (R6-validated): A[m=lane&31][k=8*(lane>>5)+j], B[k][n=lane&31],
// C/D col=lane&31, row=(reg&3)+8*(reg>>2)+4*(lane>>5).
#define GLL16(gp_, lp_) \
    __builtin_amdgcn_global_load_lds((__attribute__((address_space(1))) const void*)(gp_), \
                                     (__attribute__((address_space(3))) void*)(lp_), 16, 0, 0)

__global__ __launch_bounds__(256, 4) void gmm_main(const float* __restrict__ x,
                                                   const __bf16* __restrict__ Lt,
                                                   const float* __restrict__ muL,
                                                   const float* __restrict__ ckh,
                                                   float* __restrict__ out) {
    __shared__ __align__(16) __bf16 sB[2 * 4096];   // 2 bufs x 8KB, seg-swizzled rows
    __shared__ __align__(16) float  sOutT[KB][256]; // [k][row]: conflict-free both directions
    __shared__ float sCk[KB];

    const int tid  = threadIdx.x;
    const int wave = tid >> 6, lane = tid & 63;
    const int hp   = lane >> 5;                     // half-wave id
    const int l31  = lane & 31;
    const int r8   = lane >> 3, s8 = lane & 7;
    const int row0 = blockIdx.x * 256;
    const int rowW = row0 + wave * 64;
    const int k0   = blockIdx.y * KB;
    char* sBc = (char*)sB;

    // --- stage Lt_{k0} into buf0 (8 insts across 4 waves; validated swizzle) ---
    {
        const __bf16* L0 = Lt + (size_t)k0 * 4096;
        #pragma unroll
        for (int i = 0; i < 2; ++i) {
            int t = wave * 2 + i;
            GLL16(L0 + (size_t)(t * 8 + r8) * 64 + (s8 ^ r8) * 8, sBc + t * 1024);
        }
    }
    if (tid < KB) sCk[tid] = ckh[k0 + tid] + ckh[KC + k0 + tid] + CBASE;

    // --- mu fragments: lane holds muL[(k0+kk)*64 + et*32 + l31] as bf16, hp==0 lanes only ---
    bf16x8 mubv[2];   // [et], element index = kk
    #pragma unroll
    for (int et = 0; et < 2; ++et)
        #pragma unroll
        for (int kk = 0; kk < KB; ++kk) {
            float v = muL[(size_t)(k0 + kk) * 64 + et * 32 + l31];
            mubv[et][kk] = (hp == 0) ? (__bf16)v : (__bf16)0.f;
        }
    // constant B_mu fragment: -1 in k-slot 0 (hp==0, j==0), else 0
    bf16x8 afmu = (bf16x8)(__bf16)0.f;
    afmu[0] = (hp == 0) ? (__bf16)(-1.0f) : (__bf16)0.f;

    // --- B-fragments: 64 x-rows per wave, f32 -> bf16 in regs ---
    // af[rt][ki]: x[rowW + 32rt + l31][16ki + 8hp + j]
    bf16x8 af[2][4];
    #pragma unroll
    for (int rt = 0; rt < 2; ++rt) {
        const float* xr = x + (size_t)(rowW + 32 * rt + l31) * 64 + 8 * hp;
        #pragma unroll
        for (int ki = 0; ki < 4; ++ki) {
            float4 v0 = *(const float4*)(xr + 16 * ki);
            float4 v1 = *(const float4*)(xr + 16 * ki + 4);
            bf16x8 a;
            a[0] = (__bf16)v0.x; a[1] = (__bf16)v0.y; a[2] = (__bf16)v0.z; a[3] = (__bf16)v0.w;
            a[4] = (__bf16)v1.x; a[5] = (__bf16)v1.y; a[6] = (__bf16)v1.z; a[7] = (__bf16)v1.w;
            af[rt][ki] = a;
        }
    }

    #pragma unroll
    for (int kk = 0; kk < KB; ++kk) {
        __syncthreads();   // buf[kk&1] ready (prefetch had full prior compute phase in flight)
        if (kk + 1 < KB) { // prefetch next k into other buffer (fire-and-forget)
            const __bf16* Ln = Lt + (size_t)(k0 + kk + 1) * 4096;
            char* dst = sBc + ((kk & 1) ^ 1) * 8192;
            #pragma unroll
            for (int i = 0; i < 2; ++i) {
                int t = wave * 2 + i;
                GLL16(Ln + (size_t)(t * 8 + r8) * 64 + (s8 ^ r8) * 8, dst + t * 1024);
            }
        }
        const char* buf = sBc + (kk & 1) * 8192;
        f32x2 p2[2] = {(f32x2){0.f, 0.f}, (f32x2){0.f, 0.f}};

        #pragma unroll
        for (int et = 0; et < 2; ++et) {
            // A-frags: e = et*32 + l31, d-seg = 2ki + hp, swizzled slot
            const int e = et * 32 + l31;
            bf16x8 lf[4];
            #pragma unroll
            for (int ki = 0; ki < 4; ++ki) {
                int slot = (2 * ki + hp) ^ (lane & 7);
                lf[ki] = *(const bf16x8*)(buf + e * 128 + (slot << 4));
            }
            // mu A-fragment for this (kk, et): muL[e] in k-slot 0
            bf16x8 lfmu = (bf16x8)(__bf16)0.f;
            lfmu[0] = mubv[et][kk];

            f32x16 acc[2];
            #pragma unroll
            for (int rt = 0; rt < 2; ++rt) {
                // chain head: acc = A_mu*B_mu + 0  ->  acc[e][row] = -muL[e]
                acc[rt] = __builtin_amdgcn_mfma_f32_32x32x16_bf16(
                    lfmu, afmu, (f32x16)0.f, 0, 0, 0);
                #pragma unroll
                for (int ki = 0; ki < 4; ++ki)
                    acc[rt] = __builtin_amdgcn_mfma_f32_32x32x16_bf16(
                        lf[ki], af[rt][ki], acc[rt], 0, 0, 0);
            }
            #pragma unroll
            for (int rt = 0; rt < 2; ++rt)
                #pragma unroll
                for (int i = 0; i < 8; ++i) {
                    f32x2 pa = {acc[rt][2 * i], acc[rt][2 * i + 1]};
                    p2[rt] += pa * pa;   // v_pk_fma_f32
                }
        }
        // lane holds e-subset per hp; partner lane^32 has complement, same col=l31
        float pr0 = p2[0][0] + p2[0][1];
        float pr1 = p2[1][0] + p2[1][1];
        pr0 += __shfl_xor(pr0, 32, 64);
        pr1 += __shfl_xor(pr1, 32, 64);
        float val = hp ? pr1 : pr0;              // row = wave*64 + 32*hp + l31 = wave*64+lane
        sOutT[kk][wave * 64 + lane] = fmaf(-0.5f, val, sCk[kk]);
    }
    __syncthreads();

    // --- flush: one row (8 contiguous k) per thread, two float4 stores (32B chunks) ---
    {
        float vals[KB];
        #pragma unroll
        for (int kk = 0; kk < KB; ++kk) vals[kk] = sOutT[kk][tid];
        f32x4 a = {vals[0], vals[1], vals[2], vals[3]};
        f32x4 b = {vals[4], vals[5], vals[6], vals[7]};
        float* op = out + (size_t)(row0 + tid) * KC + k0;
        *(f32x4*)op = a;
        *(f32x4*)(op + 4) = b;
    }
}

extern "C" void kernel_launch(void* const* d_in, const int* in_sizes, int n_in,
                              void* d_out, int out_size, void* d_ws, size_t ws_size,
                              hipStream_t stream) {
    const float* x     = (const float*)d_in[0];   // [16384, 64]
    const float* means = (const float*)d_in[1];   // [200, 64]
    const float* prec  = (const float*)d_in[2];   // [200, 64, 64]
    float* out = (float*)d_out;                   // [16384, 200]

    __bf16* Lt  = (__bf16*)d_ws;
    float*  muL = (float*)((char*)d_ws + 1638400);
    float*  ckh = (float*)((char*)d_ws + 1689600);

    prep_b<<<400, 256, 0, stream>>>(prec, means, Lt, muL, ckh);
    gmm_main<<<dim3(64, KC / KB), 256, 0, stream>>>(x, Lt, muL, ckh, out);
}

// Round 9
// 93.905 us; speedup vs baseline: 1.1241x; 1.1241x over previous
//
#include <hip/hip_runtime.h>
#include <hip/hip_bf16.h>
#include <stdint.h>

typedef __bf16 bf16x4v __attribute__((ext_vector_type(4)));
typedef __bf16 bf16x8  __attribute__((ext_vector_type(8)));
typedef float  f32x4   __attribute__((ext_vector_type(4)));
typedef float  f32x2   __attribute__((ext_vector_type(2)));
typedef float  f32x16  __attribute__((ext_vector_type(16)));

#define KC 200
#define KB 8                       // k per block (32B write chunks: L2-merge ideal)
#define CBASE (-58.8120661251f)    // -0.5 * 64 * log(2*pi)

// ws layout:
//   Ltf : bf16 [200][8][512]  fragment-order: inst=(et*4+ki), lane, j
//         value = prec^T[k][e=et*32+(lane&31)][d=16ki+8*(lane>>5)+j]      0 .. 1638400
//   muL : f32  [200][64]                                            1638400 .. 1689600
//   ckh : f32  [2][200] (partial logdets)                           1689600 .. 1691200
//   xb  : bf16 [16384][64] (x converted)                            1691200 .. 3788352

// ---------------- prepass: 400 blocks (k, e-half) + 256 blocks x->bf16 ----------------
__global__ __launch_bounds__(256) void prep(const float* __restrict__ prec,
                                            const float* __restrict__ means,
                                            const float* __restrict__ x,
                                            __bf16* __restrict__ Ltf,
                                            float* __restrict__ muL,
                                            float* __restrict__ ckh,
                                            __bf16* __restrict__ xb) {
    const int tid = threadIdx.x;
    if (blockIdx.x >= 400) {        // ---- x -> bf16 (1M elems over 256 blocks) ----
        const size_t base = (size_t)(blockIdx.x - 400) * 4096;
        #pragma unroll
        for (int r = 0; r < 4; ++r) {
            size_t idx = base + r * 1024 + tid * 4;
            float4 v = *(const float4*)(x + idx);
            bf16x4v o = {(__bf16)v.x, (__bf16)v.y, (__bf16)v.z, (__bf16)v.w};
            *(bf16x4v*)(xb + idx) = o;
        }
        return;
    }
    __shared__ float sP[64][40];   // [d][e-in-half], padded
    __shared__ float sM[64];
    const int k = blockIdx.x >> 1, h = blockIdx.x & 1;
    const float* pk = prec + (size_t)k * 4096 + h * 32;
    #pragma unroll
    for (int it = 0; it < 2; ++it) {
        int f4 = tid + it * 256;            // 512 float4 = 64 rows x 8
        int d = f4 >> 3, c = (f4 & 7) * 4;
        float4 v = *(const float4*)(pk + (size_t)d * 64 + c);
        *(float4*)&sP[d][c] = v;
    }
    if (tid < 16) *(float4*)&sM[tid * 4] = ((const float4*)(means + (size_t)k * 64))[tid];
    __syncthreads();
    {   // fragment-order write: inst=(h*4+ki), lane, j -> sP[16ki+8hp+j][l31]
        int lane = tid & 63, ki = tid >> 6;
        int hp = lane >> 5, l31 = lane & 31;
        bf16x8 o;
        #pragma unroll
        for (int j = 0; j < 8; ++j) o[j] = (__bf16)sP[16 * ki + 8 * hp + j][l31];
        *(bf16x8*)(Ltf + (size_t)k * 4096 + (h * 4 + ki) * 512 + lane * 8) = o;
    }
    if (tid < 32) {
        int e = tid;
        float m = 0.f;
        #pragma unroll 8
        for (int d = 0; d < 64; ++d) m = fmaf(sM[d], sP[d][e], m);
        muL[k * 64 + h * 32 + e] = m;
        float l = __logf(sP[h * 32 + e][e]);   // diag entry (h*32+e, h*32+e)
        #pragma unroll
        for (int mm = 16; mm >= 1; mm >>= 1) l += __shfl_xor(l, mm, 64);
        if (e == 0) ckh[h * KC + k] = l;
    }
}

// ---------------- main: wave<->k decomposition, barrier-free K-loop ----------------
// acc[e][row] = Lt_k . x^T - muL (C operand = -muL). A = Lt (regs, from global),
// B = x rows (LDS, staged once, shared by all 4 waves). 32x32x16 layouts (R6-validated):
// A[m=lane&31][k=8*(lane>>5)+j], B[k][n=lane&31], C/D col=lane&31, row=(reg&3)+8*(reg>>2)+4*(lane>>5).
#define GLL16(gp_, lp_) \
    __builtin_amdgcn_global_load_lds((__attribute__((address_space(1))) const void*)(gp_), \
                                     (__attribute__((address_space(3))) void*)(lp_), 16, 0, 0)

__global__ __launch_bounds__(256, 4) void gmm_main(const __bf16* __restrict__ xb,
                                                   const __bf16* __restrict__ Ltf,
                                                   const float* __restrict__ muL,
                                                   const float* __restrict__ ckh,
                                                   float* __restrict__ out) {
    __shared__ __align__(16) __bf16 sX[256 * 64];    // 32 KB, seg-swizzled rows
    __shared__ __align__(16) float  sOutT[KB][256];  // 8 KB  (total 40960 B -> 4 blocks/CU)

    const int tid  = threadIdx.x;
    const int wave = tid >> 6, lane = tid & 63;
    const int hp   = lane >> 5;
    const int l31  = lane & 31;
    const int r8   = lane >> 3, s8 = lane & 7;
    const int row0 = blockIdx.x * 256;
    const int k0   = blockIdx.y * KB;
    char* sXc = (char*)sX;

    // --- stage x tile: 32 GLL16 (1 KB each), swizzle in source addresses ---
    #pragma unroll
    for (int i = 0; i < 8; ++i) {
        int t = wave * 8 + i;                 // 8-row group
        GLL16(xb + (size_t)(row0 + t * 8 + r8) * 64 + (s8 ^ r8) * 8, sXc + t * 1024);
    }
    __syncthreads();

    #pragma unroll
    for (int ks = 0; ks < 2; ++ks) {
        const int k  = k0 + wave * 2 + ks;    // wave-uniform
        const int kl = wave * 2 + ks;
        // Lt fragments: 8 coalesced b128 from fragment-order layout (L2-hot)
        bf16x8 lf[2][4];
        #pragma unroll
        for (int et = 0; et < 2; ++et)
            #pragma unroll
            for (int ki = 0; ki < 4; ++ki)
                lf[et][ki] = *(const bf16x8*)(Ltf + (size_t)k * 4096 + (et * 4 + ki) * 512 + lane * 8);
        // c0 = -muL in C/D layout: reg r=4*q2+i -> e = et*32 + 8*q2 + 4*hp + i
        f32x16 c0[2];
        #pragma unroll
        for (int et = 0; et < 2; ++et)
            #pragma unroll
            for (int q2 = 0; q2 < 4; ++q2) {
                f32x4 m = *(const f32x4*)(muL + (size_t)k * 64 + et * 32 + 8 * q2 + 4 * hp);
                c0[et][4 * q2 + 0] = -m[0]; c0[et][4 * q2 + 1] = -m[1];
                c0[et][4 * q2 + 2] = -m[2]; c0[et][4 * q2 + 3] = -m[3];
            }
        const float ck = ckh[k] + ckh[KC + k] + CBASE;   // scalar loads

        #pragma unroll
        for (int rt = 0; rt < 8; ++rt) {      // 8 tiles of 32 rows, no barriers
            bf16x8 xf[4];
            #pragma unroll
            for (int ki = 0; ki < 4; ++ki)
                xf[ki] = *(const bf16x8*)(sXc + (rt * 32 + l31) * 128
                                          + (((2 * ki + hp) ^ (l31 & 7)) << 4));
            f32x16 a0 = __builtin_amdgcn_mfma_f32_32x32x16_bf16(lf[0][0], xf[0], c0[0], 0, 0, 0);
            f32x16 a1 = __builtin_amdgcn_mfma_f32_32x32x16_bf16(lf[1][0], xf[0], c0[1], 0, 0, 0);
            #pragma unroll
            for (int ki = 1; ki < 4; ++ki) {
                a0 = __builtin_amdgcn_mfma_f32_32x32x16_bf16(lf[0][ki], xf[ki], a0, 0, 0, 0);
                a1 = __builtin_amdgcn_mfma_f32_32x32x16_bf16(lf[1][ki], xf[ki], a1, 0, 0, 0);
            }
            f32x2 p2 = {0.f, 0.f};
            #pragma unroll
            for (int i = 0; i < 8; ++i) {
                f32x2 u = {a0[2 * i], a0[2 * i + 1]};
                f32x2 v = {a1[2 * i], a1[2 * i + 1]};
                p2 += u * u;     // v_pk_fma_f32
                p2 += v * v;
            }
            float pr = p2[0] + p2[1];
            pr += __shfl_xor(pr, 32, 64);     // combine hp-halves: full sum over 64 e
            if (hp == 0) sOutT[kl][rt * 32 + l31] = fmaf(-0.5f, pr, ck);
        }
    }
    __syncthreads();

    // --- flush: one row (8 contiguous k) per thread, two float4 stores (32B chunks) ---
    {
        float vals[KB];
        #pragma unroll
        for (int kk = 0; kk < KB; ++kk) vals[kk] = sOutT[kk][tid];
        f32x4 a = {vals[0], vals[1], vals[2], vals[3]};
        f32x4 b = {vals[4], vals[5], vals[6], vals[7]};
        float* op = out + (size_t)(row0 + tid) * KC + k0;
        *(f32x4*)op = a;
        *(f32x4*)(op + 4) = b;
    }
}

extern "C" void kernel_launch(void* const* d_in, const int* in_sizes, int n_in,
                              void* d_out, int out_size, void* d_ws, size_t ws_size,
                              hipStream_t stream) {
    const float* x     = (const float*)d_in[0];   // [16384, 64]
    const float* means = (const float*)d_in[1];   // [200, 64]
    const float* prec  = (const float*)d_in[2];   // [200, 64, 64]
    float* out = (float*)d_out;                   // [16384, 200]

    __bf16* Ltf = (__bf16*)d_ws;
    float*  muL = (float*)((char*)d_ws + 1638400);
    float*  ckh = (float*)((char*)d_ws + 1689600);
    __bf16* xb  = (__bf16*)((char*)d_ws + 1691200);

    prep<<<656, 256, 0, stream>>>(prec, means, x, Ltf, muL, ckh, xb);
    gmm_main<<<dim3(64, KC / KB), 256, 0, stream>>>(xb, Ltf, muL, ckh, out);
}

// Round 10
// 93.651 us; speedup vs baseline: 1.1271x; 1.0027x over previous
//
#include <hip/hip_runtime.h>
#include <hip/hip_bf16.h>
#include <stdint.h>

typedef __bf16 bf16x4v __attribute__((ext_vector_type(4)));
typedef __bf16 bf16x8  __attribute__((ext_vector_type(8)));
typedef float  f32x4   __attribute__((ext_vector_type(4)));
typedef float  f32x2   __attribute__((ext_vector_type(2)));
typedef float  f32x16  __attribute__((ext_vector_type(16)));

#define KC 200
#define KB 8                       // k per block (32B write chunks: L2-merge ideal)
#define CBASE (-58.8120661251f)    // -0.5 * 64 * log(2*pi)

// ws layout:
//   Ltf : bf16 [200][8][512]  fragment-order: inst=(et*4+ki), lane, j
//         value = prec^T[k][e=et*32+(lane&31)][d=16ki+8*(lane>>5)+j]      0 .. 1638400
//   muL : f32  [200][64]                                            1638400 .. 1689600
//   ckh : f32  [2][200] (partial logdets)                           1689600 .. 1691200
//   xb  : bf16 [16384][64] (x converted)                            1691200 .. 3788352

// ---------------- prepass: 400 blocks (k, e-half) + 256 blocks x->bf16 ----------------
__global__ __launch_bounds__(256) void prep(const float* __restrict__ prec,
                                            const float* __restrict__ means,
                                            const float* __restrict__ x,
                                            __bf16* __restrict__ Ltf,
                                            float* __restrict__ muL,
                                            float* __restrict__ ckh,
                                            __bf16* __restrict__ xb) {
    const int tid = threadIdx.x;
    if (blockIdx.x >= 400) {        // ---- x -> bf16 (1M elems over 256 blocks) ----
        const size_t base = (size_t)(blockIdx.x - 400) * 4096;
        #pragma unroll
        for (int r = 0; r < 4; ++r) {
            size_t idx = base + r * 1024 + tid * 4;
            float4 v = *(const float4*)(x + idx);
            bf16x4v o = {(__bf16)v.x, (__bf16)v.y, (__bf16)v.z, (__bf16)v.w};
            *(bf16x4v*)(xb + idx) = o;
        }
        return;
    }
    __shared__ float sP[64][40];   // [d][e-in-half], padded
    __shared__ float sM[64];
    const int k = blockIdx.x >> 1, h = blockIdx.x & 1;
    const float* pk = prec + (size_t)k * 4096 + h * 32;
    #pragma unroll
    for (int it = 0; it < 2; ++it) {
        int f4 = tid + it * 256;            // 512 float4 = 64 rows x 8
        int d = f4 >> 3, c = (f4 & 7) * 4;
        float4 v = *(const float4*)(pk + (size_t)d * 64 + c);
        *(float4*)&sP[d][c] = v;
    }
    if (tid < 16) *(float4*)&sM[tid * 4] = ((const float4*)(means + (size_t)k * 64))[tid];
    __syncthreads();
    {   // fragment-order write: inst=(h*4+ki), lane, j -> sP[16ki+8hp+j][l31]
        int lane = tid & 63, ki = tid >> 6;
        int hp = lane >> 5, l31 = lane & 31;
        bf16x8 o;
        #pragma unroll
        for (int j = 0; j < 8; ++j) o[j] = (__bf16)sP[16 * ki + 8 * hp + j][l31];
        *(bf16x8*)(Ltf + (size_t)k * 4096 + (h * 4 + ki) * 512 + lane * 8) = o;
    }
    if (tid < 32) {
        int e = tid;
        float m = 0.f;
        #pragma unroll 8
        for (int d = 0; d < 64; ++d) m = fmaf(sM[d], sP[d][e], m);
        muL[k * 64 + h * 32 + e] = m;
        float l = __logf(sP[h * 32 + e][e]);   // diag entry (h*32+e, h*32+e)
        #pragma unroll
        for (int mm = 16; mm >= 1; mm >>= 1) l += __shfl_xor(l, mm, 64);
        if (e == 0) ckh[h * KC + k] = l;
    }
}

// ---------------- main: wave<->k decomposition, 128-row blocks ----------------
// acc[e][row] = Lt_k . x^T - muL (C operand = -muL). A = Lt (regs, from global, issued
// pre-barrier), B = x rows (LDS, staged once, shared by all 4 waves). 32x32x16 layouts
// (R6/R9-validated): A[m=lane&31][k=8*(lane>>5)+j], B[k][n=lane&31],
// C/D col=lane&31, row=(reg&3)+8*(reg>>2)+4*(lane>>5).
#define GLL16(gp_, lp_) \
    __builtin_amdgcn_global_load_lds((__attribute__((address_space(1))) const void*)(gp_), \
                                     (__attribute__((address_space(3))) void*)(lp_), 16, 0, 0)

__global__ __launch_bounds__(256, 4) void gmm_main(const __bf16* __restrict__ xb,
                                                   const __bf16* __restrict__ Ltf,
                                                   const float* __restrict__ muL,
                                                   const float* __restrict__ ckh,
                                                   float* __restrict__ out) {
    __shared__ __align__(16) __bf16 sX[128 * 64];    // 16 KB, seg-swizzled rows
    __shared__ __align__(16) float  sOutT[KB][128];  // 4 KB  (total 20.5 KB)

    const int tid  = threadIdx.x;
    const int wave = tid >> 6, lane = tid & 63;
    const int hp   = lane >> 5;
    const int l31  = lane & 31;
    const int r8   = lane >> 3, s8 = lane & 7;
    const int row0 = blockIdx.x * 128;
    const int k0   = blockIdx.y * KB;
    char* sXc = (char*)sX;

    // --- stage x tile: 16 GLL16 (1 KB each), swizzle in source addresses ---
    #pragma unroll
    for (int i = 0; i < 4; ++i) {
        int t = wave * 4 + i;                 // 8-row group, t = 0..15
        GLL16(xb + (size_t)(row0 + t * 8 + r8) * 64 + (s8 ^ r8) * 8, sXc + t * 1024);
    }

    // --- pre-barrier prefetch: first k's fragments + mu + ck (in flight across barrier) ---
    const int kA = k0 + wave * 2;
    bf16x8 lf[2][4];
    #pragma unroll
    for (int et = 0; et < 2; ++et)
        #pragma unroll
        for (int ki = 0; ki < 4; ++ki)
            lf[et][ki] = *(const bf16x8*)(Ltf + (size_t)kA * 4096 + (et * 4 + ki) * 512 + lane * 8);
    f32x16 c0[2];
    #pragma unroll
    for (int et = 0; et < 2; ++et)
        #pragma unroll
        for (int q2 = 0; q2 < 4; ++q2) {
            f32x4 m = *(const f32x4*)(muL + (size_t)kA * 64 + et * 32 + 8 * q2 + 4 * hp);
            c0[et][4 * q2 + 0] = -m[0]; c0[et][4 * q2 + 1] = -m[1];
            c0[et][4 * q2 + 2] = -m[2]; c0[et][4 * q2 + 3] = -m[3];
        }
    float ck = ckh[kA] + ckh[KC + kA] + CBASE;

    __syncthreads();

    #pragma unroll
    for (int ks = 0; ks < 2; ++ks) {
        const int kl = wave * 2 + ks;
        if (ks == 1) {   // reload fragments for second k (L2-hot)
            const int kB_ = k0 + wave * 2 + 1;
            #pragma unroll
            for (int et = 0; et < 2; ++et)
                #pragma unroll
                for (int ki = 0; ki < 4; ++ki)
                    lf[et][ki] = *(const bf16x8*)(Ltf + (size_t)kB_ * 4096 + (et * 4 + ki) * 512 + lane * 8);
            #pragma unroll
            for (int et = 0; et < 2; ++et)
                #pragma unroll
                for (int q2 = 0; q2 < 4; ++q2) {
                    f32x4 m = *(const f32x4*)(muL + (size_t)kB_ * 64 + et * 32 + 8 * q2 + 4 * hp);
                    c0[et][4 * q2 + 0] = -m[0]; c0[et][4 * q2 + 1] = -m[1];
                    c0[et][4 * q2 + 2] = -m[2]; c0[et][4 * q2 + 3] = -m[3];
                }
            ck = ckh[kB_] + ckh[KC + kB_] + CBASE;
        }

        #pragma unroll
        for (int rt = 0; rt < 4; ++rt) {      // 4 tiles of 32 rows, no barriers
            bf16x8 xf[4];
            #pragma unroll
            for (int ki = 0; ki < 4; ++ki)
                xf[ki] = *(const bf16x8*)(sXc + (rt * 32 + l31) * 128
                                          + (((2 * ki + hp) ^ (l31 & 7)) << 4));
            f32x16 a0 = __builtin_amdgcn_mfma_f32_32x32x16_bf16(lf[0][0], xf[0], c0[0], 0, 0, 0);
            f32x16 a1 = __builtin_amdgcn_mfma_f32_32x32x16_bf16(lf[1][0], xf[0], c0[1], 0, 0, 0);
            #pragma unroll
            for (int ki = 1; ki < 4; ++ki) {
                a0 = __builtin_amdgcn_mfma_f32_32x32x16_bf16(lf[0][ki], xf[ki], a0, 0, 0, 0);
                a1 = __builtin_amdgcn_mfma_f32_32x32x16_bf16(lf[1][ki], xf[ki], a1, 0, 0, 0);
            }
            f32x2 p2 = {0.f, 0.f};
            #pragma unroll
            for (int i = 0; i < 8; ++i) {
                f32x2 u = {a0[2 * i], a0[2 * i + 1]};
                f32x2 v = {a1[2 * i], a1[2 * i + 1]};
                p2 += u * u;     // v_pk_fma_f32
                p2 += v * v;
            }
            float pr = p2[0] + p2[1];
            pr += __shfl_xor(pr, 32, 64);     // combine hp-halves: full sum over 64 e
            if (hp == 0) sOutT[kl][rt * 32 + l31] = fmaf(-0.5f, pr, ck);
        }
    }
    __syncthreads();

    // --- flush: thread t -> row t/2, k-half t&1: one float4 (pairs merge to 32B) ---
    {
        const int r = tid >> 1, h = tid & 1;
        f32x4 a;
        #pragma unroll
        for (int j = 0; j < 4; ++j) a[j] = sOutT[h * 4 + j][r];
        *(f32x4*)(out + (size_t)(row0 + r) * KC + k0 + h * 4) = a;
    }
}

extern "C" void kernel_launch(void* const* d_in, const int* in_sizes, int n_in,
                              void* d_out, int out_size, void* d_ws, size_t ws_size,
                              hipStream_t stream) {
    const float* x     = (const float*)d_in[0];   // [16384, 64]
    const float* means = (const float*)d_in[1];   // [200, 64]
    const float* prec  = (const float*)d_in[2];   // [200, 64, 64]
    float* out = (float*)d_out;                   // [16384, 200]

    __bf16* Ltf = (__bf16*)d_ws;
    float*  muL = (float*)((char*)d_ws + 1638400);
    float*  ckh = (float*)((char*)d_ws + 1689600);
    __bf16* xb  = (__bf16*)((char*)d_ws + 1691200);

    prep<<<656, 256, 0, stream>>>(prec, means, x, Ltf, muL, ckh, xb);
    gmm_main<<<dim3(128, KC / KB), 256, 0, stream>>>(xb, Ltf, muL, ckh, out);
}

// Round 11
// 93.348 us; speedup vs baseline: 1.1308x; 1.0032x over previous
//
#include <hip/hip_runtime.h>
#include <hip/hip_bf16.h>
#include <stdint.h>

typedef __bf16 bf16x4v __attribute__((ext_vector_type(4)));
typedef __bf16 bf16x8  __attribute__((ext_vector_type(8)));
typedef float  f32x4   __attribute__((ext_vector_type(4)));
typedef float  f32x2   __attribute__((ext_vector_type(2)));
typedef float  f32x16  __attribute__((ext_vector_type(16)));

#define KC 200
#define KB 8                       // k per block (32B write chunks: L2-merge ideal)
#define CBASE (-58.8120661251f)    // -0.5 * 64 * log(2*pi)

// ws layout:
//   Ltf : bf16 [200][8][512]  fragment-order: inst=(et*4+ki), lane, j
//         value = prec^T[k][e=et*32+(lane&31)][d=16ki+8*(lane>>5)+j]      0 .. 1638400
//   muL : f32  [200][64]                                            1638400 .. 1689600
//   ckh : f32  [2][200] (partial logdets)                           1689600 .. 1691200
//   xb  : bf16 [16384][64] (x converted)                            1691200 .. 3788352

// ---------------- prepass: 400 blocks (k, e-half) + 256 blocks x->bf16 ----------------
__global__ __launch_bounds__(256) void prep(const float* __restrict__ prec,
                                            const float* __restrict__ means,
                                            const float* __restrict__ x,
                                            __bf16* __restrict__ Ltf,
                                            float* __restrict__ muL,
                                            float* __restrict__ ckh,
                                            __bf16* __restrict__ xb) {
    const int tid = threadIdx.x;
    if (blockIdx.x >= 400) {        // ---- x -> bf16 (1M elems over 256 blocks) ----
        const size_t base = (size_t)(blockIdx.x - 400) * 4096;
        #pragma unroll
        for (int r = 0; r < 4; ++r) {
            size_t idx = base + r * 1024 + tid * 4;
            float4 v = *(const float4*)(x + idx);
            bf16x4v o = {(__bf16)v.x, (__bf16)v.y, (__bf16)v.z, (__bf16)v.w};
            *(bf16x4v*)(xb + idx) = o;
        }
        return;
    }
    __shared__ float sP[64][40];   // [d][e-in-half], padded
    __shared__ float sM[64];
    const int k = blockIdx.x >> 1, h = blockIdx.x & 1;
    const float* pk = prec + (size_t)k * 4096 + h * 32;
    #pragma unroll
    for (int it = 0; it < 2; ++it) {
        int f4 = tid + it * 256;            // 512 float4 = 64 rows x 8
        int d = f4 >> 3, c = (f4 & 7) * 4;
        float4 v = *(const float4*)(pk + (size_t)d * 64 + c);
        *(float4*)&sP[d][c] = v;
    }
    if (tid < 16) *(float4*)&sM[tid * 4] = ((const float4*)(means + (size_t)k * 64))[tid];
    __syncthreads();
    {   // fragment-order write: inst=(h*4+ki), lane, j -> sP[16ki+8hp+j][l31]
        int lane = tid & 63, ki = tid >> 6;
        int hp = lane >> 5, l31 = lane & 31;
        bf16x8 o;
        #pragma unroll
        for (int j = 0; j < 8; ++j) o[j] = (__bf16)sP[16 * ki + 8 * hp + j][l31];
        *(bf16x8*)(Ltf + (size_t)k * 4096 + (h * 4 + ki) * 512 + lane * 8) = o;
    }
    if (tid < 32) {
        int e = tid;
        float m = 0.f;
        #pragma unroll 8
        for (int d = 0; d < 64; ++d) m = fmaf(sM[d], sP[d][e], m);
        muL[k * 64 + h * 32 + e] = m;
        float l = __logf(sP[h * 32 + e][e]);   // diag entry (h*32+e, h*32+e)
        #pragma unroll
        for (int mm = 16; mm >= 1; mm >>= 1) l += __shfl_xor(l, mm, 64);
        if (e == 0) ckh[h * KC + k] = l;
    }
}

// ---------------- main: wave<->k decomposition, 128-row blocks ----------------
// acc[e][row] = Lt_k . x^T - muL (C operand = -muL). A = Lt (regs, from global, issued
// pre-barrier), B = x rows (LDS, staged once, shared by all 4 waves). 32x32x16 layouts
// (R6/R9/R10-validated): A[m=lane&31][k=8*(lane>>5)+j], B[k][n=lane&31],
// C/D col=lane&31, row=(reg&3)+8*(reg>>2)+4*(lane>>5).
// R11: squared-sum epilogue tree-reduced (4 independent pk_fma chains) — no fast-math,
// so the compiler cannot reassociate the former 16-deep dependent chain itself.
#define GLL16(gp_, lp_) \
    __builtin_amdgcn_global_load_lds((__attribute__((address_space(1))) const void*)(gp_), \
                                     (__attribute__((address_space(3))) void*)(lp_), 16, 0, 0)

__global__ __launch_bounds__(256, 4) void gmm_main(const __bf16* __restrict__ xb,
                                                   const __bf16* __restrict__ Ltf,
                                                   const float* __restrict__ muL,
                                                   const float* __restrict__ ckh,
                                                   float* __restrict__ out) {
    __shared__ __align__(16) __bf16 sX[128 * 64];    // 16 KB, seg-swizzled rows
    __shared__ __align__(16) float  sOutT[KB][128];  // 4 KB  (total 20.5 KB)

    const int tid  = threadIdx.x;
    const int wave = tid >> 6, lane = tid & 63;
    const int hp   = lane >> 5;
    const int l31  = lane & 31;
    const int r8   = lane >> 3, s8 = lane & 7;
    const int row0 = blockIdx.x * 128;
    const int k0   = blockIdx.y * KB;
    char* sXc = (char*)sX;

    // --- stage x tile: 16 GLL16 (1 KB each), swizzle in source addresses ---
    #pragma unroll
    for (int i = 0; i < 4; ++i) {
        int t = wave * 4 + i;                 // 8-row group, t = 0..15
        GLL16(xb + (size_t)(row0 + t * 8 + r8) * 64 + (s8 ^ r8) * 8, sXc + t * 1024);
    }

    // --- pre-barrier prefetch: first k's fragments + mu + ck (in flight across barrier) ---
    const int kA = k0 + wave * 2;
    bf16x8 lf[2][4];
    #pragma unroll
    for (int et = 0; et < 2; ++et)
        #pragma unroll
        for (int ki = 0; ki < 4; ++ki)
            lf[et][ki] = *(const bf16x8*)(Ltf + (size_t)kA * 4096 + (et * 4 + ki) * 512 + lane * 8);
    f32x16 c0[2];
    #pragma unroll
    for (int et = 0; et < 2; ++et)
        #pragma unroll
        for (int q2 = 0; q2 < 4; ++q2) {
            f32x4 m = *(const f32x4*)(muL + (size_t)kA * 64 + et * 32 + 8 * q2 + 4 * hp);
            c0[et][4 * q2 + 0] = -m[0]; c0[et][4 * q2 + 1] = -m[1];
            c0[et][4 * q2 + 2] = -m[2]; c0[et][4 * q2 + 3] = -m[3];
        }
    float ck = ckh[kA] + ckh[KC + kA] + CBASE;

    __syncthreads();

    #pragma unroll
    for (int ks = 0; ks < 2; ++ks) {
        const int kl = wave * 2 + ks;
        if (ks == 1) {   // reload fragments for second k (L2-hot)
            const int kB_ = k0 + wave * 2 + 1;
            #pragma unroll
            for (int et = 0; et < 2; ++et)
                #pragma unroll
                for (int ki = 0; ki < 4; ++ki)
                    lf[et][ki] = *(const bf16x8*)(Ltf + (size_t)kB_ * 4096 + (et * 4 + ki) * 512 + lane * 8);
            #pragma unroll
            for (int et = 0; et < 2; ++et)
                #pragma unroll
                for (int q2 = 0; q2 < 4; ++q2) {
                    f32x4 m = *(const f32x4*)(muL + (size_t)kB_ * 64 + et * 32 + 8 * q2 + 4 * hp);
                    c0[et][4 * q2 + 0] = -m[0]; c0[et][4 * q2 + 1] = -m[1];
                    c0[et][4 * q2 + 2] = -m[2]; c0[et][4 * q2 + 3] = -m[3];
                }
            ck = ckh[kB_] + ckh[KC + kB_] + CBASE;
        }

        #pragma unroll
        for (int rt = 0; rt < 4; ++rt) {      // 4 tiles of 32 rows, no barriers
            bf16x8 xf[4];
            #pragma unroll
            for (int ki = 0; ki < 4; ++ki)
                xf[ki] = *(const bf16x8*)(sXc + (rt * 32 + l31) * 128
                                          + (((2 * ki + hp) ^ (l31 & 7)) << 4));
            f32x16 a0 = __builtin_amdgcn_mfma_f32_32x32x16_bf16(lf[0][0], xf[0], c0[0], 0, 0, 0);
            f32x16 a1 = __builtin_amdgcn_mfma_f32_32x32x16_bf16(lf[1][0], xf[0], c0[1], 0, 0, 0);
            #pragma unroll
            for (int ki = 1; ki < 4; ++ki) {
                a0 = __builtin_amdgcn_mfma_f32_32x32x16_bf16(lf[0][ki], xf[ki], a0, 0, 0, 0);
                a1 = __builtin_amdgcn_mfma_f32_32x32x16_bf16(lf[1][ki], xf[ki], a1, 0, 0, 0);
            }
            // --- tree-reduced squared-sum: 4 independent pk_fma chains of depth 4 ---
            f32x2 q0 = {0.f, 0.f}, q1 = {0.f, 0.f}, q2 = {0.f, 0.f}, q3 = {0.f, 0.f};
            #pragma unroll
            for (int i = 0; i < 4; ++i) {
                f32x2 u0 = {a0[2 * i],     a0[2 * i + 1]};
                f32x2 u1 = {a0[2 * i + 8], a0[2 * i + 9]};
                f32x2 v0 = {a1[2 * i],     a1[2 * i + 1]};
                f32x2 v1 = {a1[2 * i + 8], a1[2 * i + 9]};
                q0 += u0 * u0;   // v_pk_fma_f32, 4 independent accumulators
                q1 += u1 * u1;
                q2 += v0 * v0;
                q3 += v1 * v1;
            }
            f32x2 s01 = q0 + q1;
            f32x2 s23 = q2 + q3;
            f32x2 st  = s01 + s23;
            float pr  = st[0] + st[1];
            pr += __shfl_xor(pr, 32, 64);     // combine hp-halves: full sum over 64 e
            if (hp == 0) sOutT[kl][rt * 32 + l31] = fmaf(-0.5f, pr, ck);
        }
    }
    __syncthreads();

    // --- flush: thread t -> row t/2, k-half t&1: one float4 (pairs merge to 32B) ---
    {
        const int r = tid >> 1, h = tid & 1;
        f32x4 a;
        #pragma unroll
        for (int j = 0; j < 4; ++j) a[j] = sOutT[h * 4 + j][r];
        *(f32x4*)(out + (size_t)(row0 + r) * KC + k0 + h * 4) = a;
    }
}

extern "C" void kernel_launch(void* const* d_in, const int* in_sizes, int n_in,
                              void* d_out, int out_size, void* d_ws, size_t ws_size,
                              hipStream_t stream) {
    const float* x     = (const float*)d_in[0];   // [16384, 64]
    const float* means = (const float*)d_in[1];   // [200, 64]
    const float* prec  = (const float*)d_in[2];   // [200, 64, 64]
    float* out = (float*)d_out;                   // [16384, 200]

    __bf16* Ltf = (__bf16*)d_ws;
    float*  muL = (float*)((char*)d_ws + 1638400);
    float*  ckh = (float*)((char*)d_ws + 1689600);
    __bf16* xb  = (__bf16*)((char*)d_ws + 1691200);

    prep<<<656, 256, 0, stream>>>(prec, means, x, Ltf, muL, ckh, xb);
    gmm_main<<<dim3(128, KC / KB), 256, 0, stream>>>(xb, Ltf, muL, ckh, out);
}